// Round 9
// baseline (244.290 us; speedup 1.0000x reference)
//
#include <hip/hip_runtime.h>
#include <hip/hip_bf16.h>

// ---- constants ----
// B=4, S=2048, E=1024, H=16, D=64, scale = 0.125, LN eps 1e-5
#define LOG2E 1.44269504088896340736f

typedef __attribute__((ext_vector_type(8)))  short  short8;
typedef __attribute__((ext_vector_type(2)))  float  f32x2;
typedef __attribute__((ext_vector_type(4)))  float  f32x4;
typedef __attribute__((ext_vector_type(16))) float  f32x16;

__device__ __forceinline__ unsigned short f2bf(float f) {
  unsigned u = __builtin_bit_cast(unsigned, f);
  return (unsigned short)((u + 0x8000u) >> 16);
}
__device__ __forceinline__ float bf2f(unsigned short u) {
  return __builtin_bit_cast(float, (unsigned)u << 16);
}
__device__ __forceinline__ f32x2 pkadd(f32x2 a, f32x2 b) {
  f32x2 r; asm("v_pk_add_f32 %0, %1, %2" : "=v"(r) : "v"(a), "v"(b)); return r;
}
__device__ __forceinline__ unsigned cvtpk2(float a, float b) {
  unsigned r; asm("v_cvt_pk_bf16_f32 %0, %1, %2" : "=v"(r) : "v"(a), "v"(b)); return r;
}
__device__ __forceinline__ float hexp2(float x) {
  float r; asm("v_exp_f32 %0, %1" : "=v"(r) : "v"(x)); return r;
}
__device__ __forceinline__ float m3(float a, float b, float c) {
  return fmaxf(fmaxf(a, b), c);
}
__device__ __forceinline__ void gl16(const void* g, void* l) {
  __builtin_amdgcn_global_load_lds(
      (const __attribute__((address_space(1))) void*)g,
      (__attribute__((address_space(3))) void*)l, 16, 0, 0);
}

// ---------------- fused prep (unchanged from r8 — verified) ----------------
__global__ __launch_bounds__(256) void prep_all(const float* __restrict__ R,
                                                const float* __restrict__ En,
                                                const float* __restrict__ x,
                                                unsigned short* __restrict__ Rt,
                                                unsigned short* __restrict__ Et,
                                                unsigned short* __restrict__ vt,
                                                unsigned short* __restrict__ xb) {
  int id = blockIdx.x;
  int tid = threadIdx.x;
  __shared__ unsigned short t[64][65];
  if (id < 2048) {
    int bh = id >> 5, st = id & 31;
    int b = bh >> 4, h = bh & 15;
    int s0 = st * 64;
#pragma unroll
    for (int i = 0; i < 4; i++) {
      int it = i * 256 + tid;
      int row = it >> 4, c4 = (it & 15) * 4;
      size_t goff = (size_t)(b * 2048 + s0 + row) * 1024 + h * 64 + c4;
      float4 v = *(const float4*)(x + goff);
      ushort4 o;
      o.x = f2bf(v.x); o.y = f2bf(v.y); o.z = f2bf(v.z); o.w = f2bf(v.w);
      *(ushort4*)(xb + goff) = o;
      t[c4 + 0][row] = o.x; t[c4 + 1][row] = o.y;
      t[c4 + 2][row] = o.z; t[c4 + 3][row] = o.w;
    }
    __syncthreads();
    int r = tid >> 2, c4 = (tid & 3) * 16;
    short8 o0, o1;
#pragma unroll
    for (int j = 0; j < 8; j++) {
      o0[j] = (short)t[r][c4 + j];
      o1[j] = (short)t[r][c4 + 8 + j];
    }
    *(short8*)(vt + (size_t)(bh * 64 + r) * 2048 + s0 + c4) = o0;
    *(short8*)(vt + (size_t)(bh * 64 + r) * 2048 + s0 + c4 + 8) = o1;
  } else {
    int z = id - 2048;
    const float* src = (z >= 256) ? En : R;
    unsigned short* dst = (z >= 256) ? Et : Rt;
    int rem = z & 255;
    int e0 = (rem >> 4) * 64, f0 = (rem & 15) * 64;
    int r = tid >> 2, c4 = (tid & 3) * 16;
#pragma unroll
    for (int j = 0; j < 16; j += 4) {
      float4 v = *(const float4*)(src + (size_t)(e0 + r) * 1024 + f0 + c4 + j);
      t[c4 + j + 0][r] = f2bf(v.x);
      t[c4 + j + 1][r] = f2bf(v.y);
      t[c4 + j + 2][r] = f2bf(v.z);
      t[c4 + j + 3][r] = f2bf(v.w);
    }
    __syncthreads();
    short8 o0, o1;
#pragma unroll
    for (int j = 0; j < 8; j++) {
      o0[j] = (short)t[r][c4 + j];
      o1[j] = (short)t[r][c4 + 8 + j];
    }
    *(short8*)(dst + (size_t)(f0 + r) * 1024 + e0 + c4) = o0;
    *(short8*)(dst + (size_t)(f0 + r) * 1024 + e0 + c4 + 8) = o1;
  }
}

// ------------- 8-phase 256x256 projection GEMM (unchanged — verified) -------
__global__ __launch_bounds__(512, 2) void gemm8(const unsigned short* __restrict__ A,
                                                const unsigned short* __restrict__ Bw,
                                                unsigned short* __restrict__ qb,
                                                unsigned short* __restrict__ kb,
                                                float qs) {
  int m0 = blockIdx.x * 256;
  int by = blockIdx.y;
  int n0 = by * 256;
  int tid = threadIdx.x;
  int w = tid >> 6, l = tid & 63;
  int wr = w >> 2, wc = w & 3;
  int l15 = l & 15, lq = l >> 4;

  __shared__ unsigned short As[2][2][128 * 64];
  __shared__ unsigned short Bs[2][2][128 * 64];

  f32x4 acc[8][4] = {};

  int key = (l15 & 7) << 4;
  const char* pA[2];
  const char* pB[2];
#pragma unroll
  for (int kk = 0; kk < 2; kk++) {
    pA[kk] = (const char*)As + wr * 16384 + l15 * 128 + ((kk * 64 + lq * 16) ^ key);
    pB[kk] = (const char*)Bs + (wc >> 1) * 16384 + ((wc & 1) * 64 + l15) * 128 +
             ((kk * 64 + lq * 16) ^ key);
  }

#define SHALF(buf, kt, which)                                                 \
  do {                                                                        \
    const unsigned short* src_ = ((which) < 2)                                \
        ? (A  + (size_t)(m0 + ((which) & 1) * 128) * 1024)                    \
        : (Bw + (size_t)(n0 + ((which) & 1) * 128) * 1024);                   \
    char* dst_ = (char*)(((which) < 2) ? &As[buf][(which) & 1][0]             \
                                       : &Bs[buf][(which) & 1][0]);           \
    int k0_ = (kt) * 64;                                                      \
    _Pragma("unroll") for (int i_ = 0; i_ < 2; i_++) {                        \
      int flat_ = i_ * 512 + tid;                                             \
      int row_ = flat_ >> 3, ch_ = flat_ & 7;                                 \
      gl16(src_ + (size_t)row_ * 1024 + k0_ + ((ch_ ^ (row_ & 7)) << 3),      \
           dst_ + i_ * 8192 + w * 1024);                                      \
    }                                                                         \
  } while (0)

#define BARX()                                                                \
  do {                                                                        \
    __builtin_amdgcn_sched_barrier(0);                                        \
    asm volatile("" ::: "memory");                                            \
    __builtin_amdgcn_s_barrier();                                             \
    asm volatile("" ::: "memory");                                            \
    __builtin_amdgcn_sched_barrier(0);                                        \
  } while (0)

#define DSRD(buf, mq, nq)                                                     \
  short8 af[4][2]; short8 bfv[2][2];                                          \
  _Pragma("unroll") for (int mfq = 0; mfq < 4; mfq++)                         \
    _Pragma("unroll") for (int kk = 0; kk < 2; kk++)                          \
      af[mfq][kk] = *(const short8*)(pA[kk] + (buf) * 32768 + (mq) * 8192 +   \
                                     mfq * 2048);                             \
  _Pragma("unroll") for (int nfq = 0; nfq < 2; nfq++)                         \
    _Pragma("unroll") for (int kk = 0; kk < 2; kk++)                          \
      bfv[nfq][kk] = *(const short8*)(pB[kk] + (buf) * 32768 + (nq) * 4096 +  \
                                      nfq * 2048);

#define MM(mq, nq)                                                            \
  asm volatile("s_waitcnt lgkmcnt(0)" ::: "memory");                          \
  __builtin_amdgcn_sched_barrier(0);                                          \
  __builtin_amdgcn_s_setprio(1);                                              \
  _Pragma("unroll") for (int mfq = 0; mfq < 4; mfq++)                         \
    _Pragma("unroll") for (int nfq = 0; nfq < 2; nfq++)                       \
      _Pragma("unroll") for (int kk = 0; kk < 2; kk++)                        \
        acc[(mq) * 4 + mfq][(nq) * 2 + nfq] =                                 \
            __builtin_amdgcn_mfma_f32_16x16x32_bf16(                          \
                af[mfq][kk], bfv[nfq][kk],                                    \
                acc[(mq) * 4 + mfq][(nq) * 2 + nfq], 0, 0, 0);                \
  __builtin_amdgcn_s_setprio(0);

  SHALF(0, 0, 0); SHALF(0, 0, 1); SHALF(0, 0, 2); SHALF(0, 0, 3);
  asm volatile("s_waitcnt vmcnt(0)" ::: "memory");
  BARX();

  for (int kt = 0; kt < 16; kt++) {
    int buf = kt & 1, nb = buf ^ 1;
    {
      DSRD(buf, 0, 0);
      if (kt < 15) { SHALF(nb, kt + 1, 0); SHALF(nb, kt + 1, 1); }
      MM(0, 0);
      BARX();
    }
    {
      DSRD(buf, 0, 1);
      if (kt < 15) { SHALF(nb, kt + 1, 2); SHALF(nb, kt + 1, 3); }
      MM(0, 1);
      BARX();
    }
    {
      DSRD(buf, 1, 0);
      MM(1, 0);
      BARX();
    }
    {
      DSRD(buf, 1, 1);
      MM(1, 1);
      asm volatile("s_waitcnt vmcnt(0)" ::: "memory");
      BARX();
    }
  }
#undef SHALF
#undef DSRD
#undef MM
#undef BARX

  unsigned short* out = (by < 4) ? qb : kb;
  float scale = (by < 4) ? qs : 1.0f;
  int cb = (by & 3) * 256;
#pragma unroll
  for (int mf = 0; mf < 8; mf++)
#pragma unroll
    for (int nf = 0; nf < 4; nf++)
#pragma unroll
      for (int r = 0; r < 4; r++) {
        int grow = m0 + wr * 128 + mf * 16 + lq * 4 + r;
        int gcol = cb + wc * 64 + nf * 16 + l15;
        out[(size_t)grow * 1024 + gcol] = f2bf(acc[mf][nf][r] * scale);
      }
}

// ---------------- flash attention, 2-way split-KV ----------------
// 2048 blocks: sp = f>>10 picks t' half [sp*1024, sp*1024+1024) (16 tiles).
// Emits normalized partial O (bf16) into opart[sp] + per-row (m,l) float2.
// Inner loop identical to the verified round-5 form.
__global__ __launch_bounds__(256, 4) void attn_k(const unsigned short* __restrict__ Q,
                                                 const unsigned short* __restrict__ K,
                                                 const unsigned short* __restrict__ VT,
                                                 unsigned short* __restrict__ opart,
                                                 float2* __restrict__ mlb) {
  int f = blockIdx.x;
  int sp = f >> 10;
  int g = f & 1023;
  int bh = ((g >> 7) << 3) | (g & 7);   // head clustering per XCD (both splits same XCD)
  int qt = (g >> 3) & 15;
  int b = bh >> 4, h = bh & 15;
  int q0 = qt * 128;
  int tbase = sp << 10;
  int tid = threadIdx.x;
  int w = tid >> 6, l = tid & 63;
  int lh = l >> 5, l31 = l & 31;

  __shared__ unsigned short Kl[2 * 64 * 64];
  __shared__ unsigned short Vl[2 * 64 * 64];

  int qrow = q0 + w * 32 + l31;
  const unsigned short* qp = Q + (size_t)(b * 2048 + qrow) * 1024 + h * 64;
  short8 qf[4];
#pragma unroll
  for (int dk = 0; dk < 4; dk++) qf[dk] = *(const short8*)(qp + dk * 16 + lh * 8);

  int key = (l31 & 7) << 4;
  int koff[4], voff[4];
#pragma unroll
  for (int dk = 0; dk < 4; dk++) koff[dk] = l31 * 128 + ((dk * 32 + lh * 16) ^ key);
#pragma unroll
  for (int tf = 0; tf < 2; tf++)
#pragma unroll
    for (int kk = 0; kk < 2; kk++)
      voff[tf * 2 + kk] = l31 * 128 + ((tf * 64 + kk * 32 + lh * 16) ^ key);

  const char* KB = (const char*)Kl;
  const char* VB = (const char*)Vl;

  f32x16 cacc[2] = {};
  float mrun = -INFINITY, lsl = 0.f;

#define STAGE(buf, tt)                                                        \
  {                                                                           \
    _Pragma("unroll") for (int i_ = 0; i_ < 2; i_++) {                        \
      int row_ = i_ * 32 + (tid >> 3), ch_ = tid & 7;                         \
      gl16(K + (size_t)(b * 2048 + (tt) + row_) * 1024 + h * 64 +             \
               ((ch_ ^ (row_ & 7)) << 3),                                     \
           (char*)Kl + (buf) * 8192 + i_ * 4096 + w * 1024);                  \
      gl16(VT + (size_t)(bh * 64 + row_) * 2048 + (tt) +                      \
               ((ch_ ^ (row_ & 7)) << 3),                                     \
           (char*)Vl + (buf) * 8192 + i_ * 4096 + w * 1024);                  \
    }                                                                         \
  }

#define COMPUTE(IMM)                                                          \
  do {                                                                        \
    f32x16 sacc[2] = {};                                                      \
    __builtin_amdgcn_s_setprio(1);                                            \
    _Pragma("unroll") for (int tf = 0; tf < 2; tf++)                          \
      _Pragma("unroll") for (int dk = 0; dk < 4; dk++) {                      \
        short8 kf = *(const short8*)(KB + koff[dk] + (IMM) + tf * 4096);      \
        sacc[tf] = __builtin_amdgcn_mfma_f32_32x32x16_bf16(kf, qf[dk],        \
                                                           sacc[tf], 0, 0, 0);\
      }                                                                       \
    __builtin_amdgcn_s_setprio(0);                                            \
    float t16[16];                                                            \
    _Pragma("unroll") for (int j = 0; j < 16; j++)                            \
      t16[j] = fmaxf(sacc[0][j], sacc[1][j]);                                 \
    float t8[8];                                                              \
    _Pragma("unroll") for (int j = 0; j < 8; j++)                             \
      t8[j] = fmaxf(t16[j], t16[j + 8]);                                      \
    float lmax = m3(m3(t8[0], t8[1], t8[2]), m3(t8[3], t8[4], t8[5]),         \
                    fmaxf(t8[6], t8[7]));                                     \
    if (!__all(lmax <= mrun + 8.f)) {                                         \
      unsigned lu = __builtin_bit_cast(unsigned, lmax);                       \
      auto rr = __builtin_amdgcn_permlane32_swap(lu, lu, false, false);       \
      float pm = fmaxf(__builtin_bit_cast(float, rr[0]),                      \
                       __builtin_bit_cast(float, rr[1]));                     \
      float mnew = fmaxf(mrun, pm);                                           \
      float alpha = hexp2(mrun - mnew);                                       \
      mrun = mnew; lsl *= alpha;                                              \
      _Pragma("unroll") for (int r = 0; r < 16; r++) {                        \
        int rowq = (r & 3) + ((r >> 2) << 3) + (lh << 2);                     \
        float ar = __shfl(alpha, rowq, 64);                                   \
        cacc[0][r] *= ar; cacc[1][r] *= ar;                                   \
      }                                                                       \
    }                                                                         \
    f32x2 negm2; negm2[0] = -mrun; negm2[1] = -mrun;                          \
    f32x2 r2; r2[0] = 0.f; r2[1] = 0.f;                                       \
    _Pragma("unroll") for (int tf = 0; tf < 2; tf++) {                        \
      unsigned pw[8];                                                         \
      _Pragma("unroll") for (int j = 0; j < 8; j++) {                         \
        f32x2 s2; s2[0] = sacc[tf][2 * j]; s2[1] = sacc[tf][2 * j + 1];       \
        f32x2 d = pkadd(s2, negm2);                                           \
        float e0 = hexp2(d[0]), e1 = hexp2(d[1]);                             \
        f32x2 e2; e2[0] = e0; e2[1] = e1;                                     \
        r2 = pkadd(r2, e2);                                                   \
        pw[j] = cvtpk2(e0, e1);                                               \
      }                                                                       \
      short8 pa[2];                                                           \
      _Pragma("unroll") for (int kk = 0; kk < 2; kk++) {                      \
        auto r02 = __builtin_amdgcn_permlane32_swap(pw[kk * 4 + 0],           \
                                                    pw[kk * 4 + 2], false, false); \
        auto r13 = __builtin_amdgcn_permlane32_swap(pw[kk * 4 + 1],           \
                                                    pw[kk * 4 + 3], false, false); \
        union { unsigned u[4]; short8 s8; } wv;                               \
        wv.u[0] = r02[0]; wv.u[1] = r13[0];                                   \
        wv.u[2] = r02[1]; wv.u[3] = r13[1];                                   \
        pa[kk] = wv.s8;                                                       \
      }                                                                       \
      __builtin_amdgcn_s_setprio(1);                                          \
      _Pragma("unroll") for (int kk = 0; kk < 2; kk++)                        \
        _Pragma("unroll") for (int df = 0; df < 2; df++) {                    \
          short8 vf = *(const short8*)(VB + voff[tf * 2 + kk] + (IMM) +       \
                                       df * 4096);                            \
          cacc[df] = __builtin_amdgcn_mfma_f32_32x32x16_bf16(pa[kk], vf,      \
                                                             cacc[df], 0, 0, 0); \
        }                                                                     \
      __builtin_amdgcn_s_setprio(0);                                          \
    }                                                                         \
    lsl += r2[0] + r2[1];                                                     \
  } while (0)

  STAGE(0, tbase);
  __syncthreads();

  for (int tc2 = 0; tc2 < 8; tc2++) {
    int t0 = tbase + tc2 * 128;
    STAGE(1, t0 + 64);
    COMPUTE(0);
    __syncthreads();
    if (tc2 < 7) STAGE(0, t0 + 128);
    COMPUTE(8192);
    __syncthreads();
  }
#undef STAGE
#undef COMPUTE

  // epilogue: pair-combine l, store normalized partial O + (m,l)
  {
    unsigned lu = __builtin_bit_cast(unsigned, lsl);
    auto rr = __builtin_amdgcn_permlane32_swap(lu, lu, false, false);
    lsl = __builtin_bit_cast(float, rr[0]) + __builtin_bit_cast(float, rr[1]);
  }
  float linv = 1.f / lsl;
  unsigned short* op = opart + (size_t)sp * (8u << 20);
#pragma unroll
  for (int r = 0; r < 16; r++) {
    int rowq = (r & 3) + ((r >> 2) << 3) + (lh << 2);
    float lr = __shfl(linv, rowq, 64);
    size_t base = (size_t)(b * 2048 + q0 + w * 32 + rowq) * 1024 + h * 64 + l31;
    op[base]      = f2bf(cacc[0][r] * lr);
    op[base + 32] = f2bf(cacc[1][r] * lr);
  }
  if (lh == 0) {
    float2 ml; ml.x = mrun; ml.y = lsl;
    mlb[(size_t)sp * 131072 + (size_t)bh * 2048 + qrow] = ml;
  }
}

// -------- combine partials + residual + LayerNorm (wave-per-row) --------
__global__ __launch_bounds__(256) void ln_k(const unsigned short* __restrict__ opart,
                                            const float2* __restrict__ mlb,
                                            const float* __restrict__ x,
                                            const float* __restrict__ wgt,
                                            const float* __restrict__ bgam,
                                            float* __restrict__ out) {
  int w = threadIdx.x >> 6, l = threadIdx.x & 63;
  int row = blockIdx.x * 4 + w;
  int b = row >> 11, s = row & 2047;
  size_t base = (size_t)row * 1024;
  const unsigned short* o2p = opart + (8u << 20);
  float y[16];
  float sum = 0.f, ss = 0.f;
#pragma unroll
  for (int j = 0; j < 4; j++) {
    int col = j * 256 + l * 4;
    int h = j * 4 + (l >> 4);
    float2 ml1 = mlb[(size_t)(b * 16 + h) * 2048 + s];
    float2 ml2 = mlb[131072 + (size_t)(b * 16 + h) * 2048 + s];
    float mm = fmaxf(ml1.x, ml2.x);
    float w1 = ml1.y * hexp2(ml1.x - mm);
    float w2 = ml2.y * hexp2(ml2.x - mm);
    float inv = 1.f / (w1 + w2);
    float a1 = w1 * inv, a2 = w2 * inv;
    ushort4 c1 = *(const ushort4*)(opart + base + col);
    ushort4 c2 = *(const ushort4*)(o2p + base + col);
    float4 xv = *(const float4*)(x + base + col);
    float y0 = a1 * bf2f(c1.x) + a2 * bf2f(c2.x) + xv.x;
    float y1 = a1 * bf2f(c1.y) + a2 * bf2f(c2.y) + xv.y;
    float y2 = a1 * bf2f(c1.z) + a2 * bf2f(c2.z) + xv.z;
    float y3 = a1 * bf2f(c1.w) + a2 * bf2f(c2.w) + xv.w;
    y[4 * j + 0] = y0; y[4 * j + 1] = y1; y[4 * j + 2] = y2; y[4 * j + 3] = y3;
    sum += (y0 + y1) + (y2 + y3);
    ss += (y0 * y0 + y1 * y1) + (y2 * y2 + y3 * y3);
  }
#pragma unroll
  for (int o = 32; o >= 1; o >>= 1) {
    sum += __shfl_xor(sum, o, 64);
    ss  += __shfl_xor(ss, o, 64);
  }
  float mu = sum * (1.f / 1024.f);
  float var = ss * (1.f / 1024.f) - mu * mu;
  float rstd = rsqrtf(var + 1e-5f);
#pragma unroll
  for (int j = 0; j < 4; j++) {
    int col = j * 256 + l * 4;
    float4 wv = *(const float4*)(wgt + col);
    float4 bv = *(const float4*)(bgam + col);
    float4 o4;
    o4.x = (y[4 * j + 0] - mu) * rstd * wv.x + bv.x;
    o4.y = (y[4 * j + 1] - mu) * rstd * wv.y + bv.y;
    o4.z = (y[4 * j + 2] - mu) * rstd * wv.z + bv.z;
    o4.w = (y[4 * j + 3] - mu) * rstd * wv.w + bv.w;
    *(float4*)(out + base + col) = o4;
  }
}

// ---------------- launch ----------------
extern "C" void kernel_launch(void* const* d_in, const int* in_sizes, int n_in,
                              void* d_out, int out_size, void* d_ws, size_t ws_size,
                              hipStream_t stream) {
  (void)in_sizes; (void)n_in; (void)out_size; (void)ws_size;
  const float* R  = (const float*)d_in[0];
  const float* En = (const float*)d_in[1];
  const float* x  = (const float*)d_in[2];
  const float* lw = (const float*)d_in[3];
  const float* lb = (const float*)d_in[4];
  float* out = (float*)d_out;

  char* ws = (char*)d_ws;
  unsigned short* xb  = (unsigned short*)(ws);                        // 16 MB bf16 x
  unsigned short* qb  = (unsigned short*)(ws + (size_t)(16u << 20));  // 16 MB Q
  unsigned short* kb  = (unsigned short*)(ws + (size_t)(32u << 20));  // 16 MB K
  unsigned short* vt  = (unsigned short*)(ws + (size_t)(48u << 20));  // 16 MB V^T
  unsigned short* op  = (unsigned short*)(ws + (size_t)(64u << 20));  // 32 MB partial O x2
  unsigned short* rt  = (unsigned short*)(ws + (size_t)(96u << 20));  // 2 MB R^T
  unsigned short* et  = (unsigned short*)(ws + (size_t)(98u << 20));  // 2 MB E^T (contiguous)
  float2*         mlb = (float2*)(ws + (size_t)(100u << 20));         // 2 MB (m,l) x2

  prep_all<<<2560, 256, 0, stream>>>(R, En, x, rt, et, vt, xb);
  gemm8<<<dim3(32, 8), 512, 0, stream>>>(xb, rt, qb, kb, 0.125f * LOG2E);
  attn_k<<<2048, 256, 0, stream>>>(qb, kb, vt, op, mlb);
  ln_k<<<2048, 256, 0, stream>>>(op, mlb, x, lw, lb, out);
}